// Round 16
// baseline (246.462 us; speedup 1.0000x reference)
//
#include <hip/hip_runtime.h>
#include <hip/hip_bf16.h>

// ---------------------------------------------------------------------------
// PolygonPredictionLayer: B=8,P=64,N=512,T=196(->224),S=100(->112),C=256,H=8,dh=32
// R15: attn_fuse v6 = R13's 8-wave zero-LDS main loop (wave=head, swapped
//   QK^T, no K/V fetch duplication) + R14's single-buffer epilogue (61 KB LDS
//   -> 2 blocks/CU = 4 waves/SIMD, launch_bounds(512,4), reg cap 128 >= 88).
//   kvproj v9 and the rest unchanged from R12/R13.
// ---------------------------------------------------------------------------

typedef __attribute__((ext_vector_type(8))) short bf16x8;
typedef __attribute__((ext_vector_type(4))) float f32x4;

__device__ __forceinline__ float bf2f(ushort u) {
    union { float f; uint u32; } v; v.u32 = ((uint)u) << 16; return v.f;
}
__device__ __forceinline__ ushort f2bf(float f) {
    union { float f; uint u; } v; v.f = f;
    uint r = v.u + 0x7FFF + ((v.u >> 16) & 1);
    return (ushort)(r >> 16);
}
__device__ __forceinline__ uint pk2(float a, float b) {
    __hip_bfloat162 h = __float22bfloat162_rn(make_float2(a, b));
    union { __hip_bfloat162 h2; uint u; } c; c.h2 = h; return c.u;
}
__device__ __forceinline__ f32x4 MFMA(bf16x8 a, bf16x8 b, f32x4 c) {
    return __builtin_amdgcn_mfma_f32_16x16x32_bf16(a, b, c, 0, 0, 0);
}

#define SCALE_DH 0.17677669529663687f  // 1/sqrt(32)

// ---------------- prep: weights+biases -> ws tables, qcp zero ---------------
#define TOTALW (2337 * 256)
#define QCPN   (8 * 8 * 112 * 32)
#define NBIAS  2337

__global__ void prep_kernel(const float* w0, const float* w1_, const float* w2_,
                            const float* w3, const float* w4, const float* w5,
                            const float* w6, const float* w7, const float* w8,
                            const float* w9, const float* w10,
                            const float* b0, const float* b1_, const float* b2_,
                            const float* b3, const float* b4, const float* b5,
                            const float* b6, const float* b7, const float* b8,
                            const float* b9, const float* b10,
                            ushort* wbf, float* bias, ushort* qcp)
{
    for (size_t i = blockIdx.x * blockDim.x + threadIdx.x;
         i < (size_t)TOTALW + QCPN + NBIAS; i += (size_t)gridDim.x * blockDim.x) {
        if (i < TOTALW) {
            int row = (int)(i >> 8), col = (int)(i & 255);
            const float* sp; int base;
            if      (row < 256)  { sp = w0;  base = 0; }
            else if (row < 512)  { sp = w1_; base = 256; }
            else if (row < 768)  { sp = w2_; base = 512; }
            else if (row < 1024) { sp = w3;  base = 768; }
            else if (row < 1280) { sp = w4;  base = 1024; }
            else if (row < 1536) { sp = w5;  base = 1280; }
            else if (row < 1792) { sp = w6;  base = 1536; }
            else if (row < 2048) { sp = w7;  base = 1792; }
            else if (row < 2304) { sp = w8;  base = 2048; }
            else if (row < 2336) { sp = w9;  base = 2304; }
            else                 { sp = w10; base = 2336; }
            wbf[i] = f2bf(sp[(size_t)(row - base) * 256 + col]);
        } else if (i < (size_t)TOTALW + QCPN) {
            qcp[i - TOTALW] = 0;
        } else {
            int idx = (int)(i - TOTALW - QCPN);
            const float* sp; int base;
            if      (idx < 256)  { sp = b0;  base = 0; }
            else if (idx < 512)  { sp = b1_; base = 256; }
            else if (idx < 768)  { sp = b2_; base = 512; }
            else if (idx < 1024) { sp = b3;  base = 768; }
            else if (idx < 1280) { sp = b4;  base = 1024; }
            else if (idx < 1536) { sp = b5;  base = 1280; }
            else if (idx < 1792) { sp = b6;  base = 1536; }
            else if (idx < 2048) { sp = b7;  base = 1792; }
            else if (idx < 2304) { sp = b8;  base = 2048; }
            else if (idx < 2336) { sp = b9;  base = 2304; }
            else                 { sp = b10; base = 2336; }
            bias[idx] = sp[idx - base];
        }
    }
}

// ---------------- generic small GEMM: out = A @ W^T + bias -----------------
template<int ASRC, int GS, int EPI>
__global__ __launch_bounds__(256)
void gemm_rows(const void* Aptr, const ushort* Wall, const float* Ball,
               ushort* Out, int M, int Wrow0, int Brow0, int ldo)
{
    __shared__ ushort As[64 * 40];
    __shared__ ushort Bs[128 * 40];
    int tid = threadIdx.x;
    int lane = tid & 63, w = tid >> 6;
    int lr = lane & 15, lg = lane >> 4;
    int r0 = blockIdx.x * 64;
    int j0 = blockIdx.y * 128;

    f32x4 acc[4][2];
    #pragma unroll
    for (int mt = 0; mt < 4; ++mt)
        #pragma unroll
        for (int nt = 0; nt < 2; ++nt) { f32x4 z = {0.f,0.f,0.f,0.f}; acc[mt][nt] = z; }

    for (int ks = 0; ks < 8; ++ks) {
        int c0 = ks * 32;
        {
            int i = tid >> 2, q = tid & 3;
            int r = r0 + i;
            if (ASRC == 0) {
                uint4 v = make_uint4(0u,0u,0u,0u);
                if (r < M) v = *(const uint4*)((const ushort*)Aptr + (size_t)r * 256 + c0 + q * 8);
                *(uint4*)(&As[i * 40 + q * 8]) = v;
            } else {
                uint u[4] = {0u,0u,0u,0u};
                if (r < M) {
                    int g = r / GS, o = r - g * GS;
                    const float* src = (const float*)Aptr + (size_t)g * 256 * GS + o;
                    #pragma unroll
                    for (int k2 = 0; k2 < 4; ++k2) {
                        ushort a0 = f2bf(src[(size_t)(c0 + q * 8 + 2 * k2)     * GS]);
                        ushort a1 = f2bf(src[(size_t)(c0 + q * 8 + 2 * k2 + 1) * GS]);
                        u[k2] = (uint)a0 | ((uint)a1 << 16);
                    }
                }
                *(uint4*)(&As[i * 40 + q * 8]) = make_uint4(u[0], u[1], u[2], u[3]);
            }
        }
        {
            int jj = tid >> 1, half = tid & 1;
            const ushort* src = Wall + (size_t)(Wrow0 + j0 + jj) * 256 + c0 + half * 16;
            ushort* dst = &Bs[jj * 40 + half * 16];
            *(uint4*)(dst)     = *(const uint4*)(src);
            *(uint4*)(dst + 8) = *(const uint4*)(src + 8);
        }
        __syncthreads();
        bf16x8 bfr[2];
        #pragma unroll
        for (int nt = 0; nt < 2; ++nt)
            bfr[nt] = *(const bf16x8*)(&Bs[(w * 32 + nt * 16 + lr) * 40 + lg * 8]);
        #pragma unroll
        for (int mt = 0; mt < 4; ++mt) {
            bf16x8 afr = *(const bf16x8*)(&As[(mt * 16 + lr) * 40 + lg * 8]);
            acc[mt][0] = MFMA(afr, bfr[0], acc[mt][0]);
            acc[mt][1] = MFMA(afr, bfr[1], acc[mt][1]);
        }
        __syncthreads();
    }
    #pragma unroll
    for (int mt = 0; mt < 4; ++mt) {
        #pragma unroll
        for (int nt = 0; nt < 2; ++nt) {
            int jc = j0 + w * 32 + nt * 16 + lr;
            float bias = Ball[Brow0 + jc];
            #pragma unroll
            for (int rg = 0; rg < 4; ++rg) {
                int r = r0 + mt * 16 + lg * 4 + rg;
                if (r >= M) continue;
                float vv = acc[mt][nt][rg] + bias;
                if (EPI == 0) {
                    Out[(size_t)r * ldo + jc] = f2bf(vv);
                } else {
                    int b = r / 100, s = r - b * 100;
                    int h = jc >> 5, d = jc & 31;
                    Out[(((size_t)(b * 8 + h)) * 112 + s) * 32 + d] = f2bf(vv * SCALE_DH);
                }
            }
        }
    }
}

// ---------------- self-attention (tiny, VALU) ------------------------------
__global__ __launch_bounds__(128)
void self_attn(const ushort* qkv, ushort* sav)
{
    __shared__ float kls[100][33];
    __shared__ float vls[100][33];
    __shared__ float sls[100][101];
    int bh = blockIdx.x; int b = bh >> 3, h = bh & 7;
    int tid = threadIdx.x;
    for (int idx = tid; idx < 100 * 32; idx += 128) {
        int t = idx >> 5, d = idx & 31;
        kls[t][d] = bf2f(qkv[((size_t)(b * 100 + t)) * 768 + 256 + h * 32 + d]);
        vls[t][d] = bf2f(qkv[((size_t)(b * 100 + t)) * 768 + 512 + h * 32 + d]);
    }
    __syncthreads();
    if (tid < 100) {
        int s = tid;
        float q[32];
        #pragma unroll
        for (int d = 0; d < 32; ++d)
            q[d] = bf2f(qkv[((size_t)(b * 100 + s)) * 768 + h * 32 + d]) * SCALE_DH;
        float mx = -1e30f;
        for (int t = 0; t < 100; ++t) {
            float sc = 0.f;
            #pragma unroll
            for (int d = 0; d < 32; ++d) sc += q[d] * kls[t][d];
            sls[s][t] = sc; mx = fmaxf(mx, sc);
        }
        float sum = 0.f;
        for (int t = 0; t < 100; ++t) {
            float p = __expf(sls[s][t] - mx);
            sls[s][t] = p; sum += p;
        }
        float inv = 1.f / sum;
        float acc2[32];
        #pragma unroll
        for (int d = 0; d < 32; ++d) acc2[d] = 0.f;
        for (int t = 0; t < 100; ++t) {
            float pv = sls[s][t];
            #pragma unroll
            for (int d = 0; d < 32; ++d) acc2[d] += pv * vls[t][d];
        }
        #pragma unroll
        for (int d = 0; d < 32; ++d)
            sav[((size_t)(b * 100 + s)) * 256 + h * 32 + d] = f2bf(acc2[d] * inv);
    }
}

// ---------------- kvproj v9: kc[n][224][256] t-major, vc[n][256][224] ------
// One block per proposal, block 512 (8 waves), LDS featT[224][264] bf16.
// Weights persistent af[4][8]. pk2/uint2 staging. Pad skipped (13 tiles).
__global__ __launch_bounds__(512, 2)
void kvproj(const float* features, const ushort* Wall, const float* Ball,
            ushort* kc, ushort* vc, int n_base)
{
    __shared__ ushort featT[224 * 264];
    int tid = threadIdx.x;
    int lane = tid & 63, w = tid >> 6;
    int lr = lane & 15, lg = lane >> 4;
    int nl = blockIdx.x;
    int n  = n_base + nl;
    const float* fb = features + (size_t)n * 256 * 196;

    bf16x8 af[4][8];
    #pragma unroll
    for (int m = 0; m < 4; ++m) {
        int row = ((m < 2) ? 1280 : 1536) + w * 32 + (m & 1) * 16 + lr;
        #pragma unroll
        for (int ks = 0; ks < 8; ++ks)
            af[m][ks] = *(const bf16x8*)(Wall + (size_t)row * 256 + ks * 32 + lg * 8);
    }
    float biask0 = Ball[1280 + w * 32 + lr];
    float biask1 = Ball[1296 + w * 32 + lr];
    float biasv0 = Ball[1536 + w * 32 + lr];
    float biasv1 = Ball[1552 + w * 32 + lr];

    #pragma unroll
    for (int it = 0; it < 7; ++it) {
        int idx = tid + it * 512;
        if (idx < 3136) {
            int cg = idx / 49, tq = idx - cg * 49;
            const float* p = fb + (size_t)(cg * 4) * 196 + tq * 4;
            float4 v0 = *(const float4*)(p);
            float4 v1 = *(const float4*)(p + 196);
            float4 v2 = *(const float4*)(p + 392);
            float4 v3 = *(const float4*)(p + 588);
            #pragma unroll
            for (int j = 0; j < 4; ++j) {
                float e0 = (j == 0) ? v0.x : (j == 1) ? v0.y : (j == 2) ? v0.z : v0.w;
                float e1 = (j == 0) ? v1.x : (j == 1) ? v1.y : (j == 2) ? v1.z : v1.w;
                float e2 = (j == 0) ? v2.x : (j == 1) ? v2.y : (j == 2) ? v2.z : v2.w;
                float e3 = (j == 0) ? v3.x : (j == 1) ? v3.y : (j == 2) ? v3.z : v3.w;
                uint2 pr;
                pr.x = pk2(e0, e1);
                pr.y = pk2(e2, e3);
                *(uint2*)(&featT[(tq * 4 + j) * 264 + cg * 4]) = pr;
            }
        }
    }
    for (int idx = tid; idx < 12 * 264; idx += 512)
        featT[196 * 264 + idx] = 0;
    __syncthreads();   // the only barrier

    for (int tt = 0; tt < 13; ++tt) {
        bf16x8 a8[8];
        #pragma unroll
        for (int ks = 0; ks < 8; ++ks)
            a8[ks] = *(const bf16x8*)(&featT[(tt * 16 + lr) * 264 + ks * 32 + lg * 8]);
        f32x4 acc[4];
        #pragma unroll
        for (int m = 0; m < 4; ++m) { f32x4 z = {0.f,0.f,0.f,0.f}; acc[m] = z; }
        #pragma unroll
        for (int ks = 0; ks < 8; ++ks)
            #pragma unroll
            for (int m = 0; m < 4; ++m)
                acc[m] = MFMA(a8[ks], af[m][ks], acc[m]);

        int tb = tt * 16 + lg * 4;
        #pragma unroll
        for (int rg = 0; rg < 4; ++rg) {
            int t = tb + rg;
            if (t < 196) {
                kc[((size_t)nl * 224 + t) * 256 + w * 32 + lr]      = f2bf(acc[0][rg] + biask0);
                kc[((size_t)nl * 224 + t) * 256 + w * 32 + 16 + lr] = f2bf(acc[1][rg] + biask1);
            }
        }
        if (tb < 196) {
            size_t vb0 = ((size_t)nl * 256 + w * 32 + lr) * 224 + tb;
            size_t vb1 = ((size_t)nl * 256 + w * 32 + 16 + lr) * 224 + tb;
            uint a01 = pk2(acc[2][0] + biasv0, acc[2][1] + biasv0);
            uint a23 = pk2(acc[2][2] + biasv0, acc[2][3] + biasv0);
            uint b01 = pk2(acc[3][0] + biasv1, acc[3][1] + biasv1);
            uint b23 = pk2(acc[3][2] + biasv1, acc[3][3] + biasv1);
            *(uint*)(vc + vb0)     = a01;
            *(uint*)(vc + vb0 + 2) = a23;
            *(uint*)(vc + vb1)     = b01;
            *(uint*)(vc + vb1 + 2) = b23;
        }
    }
}

// ---------------- attn_fuse v6: 8 waves, single-buffer epilogue ------------
// block 512 (8 waves, wave = head). Main loop = R13 (swapped QK^T, P in regs,
// zero LDS, T14 prefetch). Epilogue overlays ONE buffer OB[112][264]:
// O -> (oproj reads) -> O2 -> (h1 reads + score head) -> h1. LDS 60928 B ->
// 2 blocks/CU (launch_bounds(512,4), reg cap 128 >= 88 measured).
__global__ __launch_bounds__(512, 4)
void attn_fuse(const ushort* qcp, const ushort* kc, const ushort* vc,
               const ushort* Wall, const float* Ball, float* outp, int n_base)
{
    __shared__ char smem[60928];
    ushort* OB  = (ushort*)smem;
    float* hbar = (float*)(smem + 59392);
    float* scb  = (float*)(smem + 60416);

    int tid = threadIdx.x;
    int lane = tid & 63; int w = tid >> 6;             // w = head
    int lr = lane & 15, lg = lane >> 4;
    int nl = blockIdx.x; int n = n_base + nl;
    int b = n >> 6;
    const ushort* kcn = kc + (size_t)nl * 224 * 256;
    const ushort* vcn = vc + (size_t)nl * 256 * 224;

    bf16x8 qf[7];
    #pragma unroll
    for (int mt = 0; mt < 7; ++mt)
        qf[mt] = *(const bf16x8*)(qcp + ((((size_t)(b * 8 + w)) * 112 + mt * 16 + lr) * 32 + lg * 8));

    bf16x8 ones;
    #pragma unroll
    for (int j = 0; j < 8; ++j) ones[j] = (short)0x3F80;

    f32x4 o_acc[7][2], l_acc[7];
    #pragma unroll
    for (int mt = 0; mt < 7; ++mt) {
        f32x4 z = {0.f,0.f,0.f,0.f};
        o_acc[mt][0] = z; o_acc[mt][1] = z; l_acc[mt] = z;
    }

    const ushort* kbase = kcn + (size_t)lr * 256 + w * 32 + lg * 8;
    const ushort* vb0 = vcn + ((size_t)(w * 32 + lr)) * 224;
    const ushort* vb1 = vcn + ((size_t)(w * 32 + 16 + lr)) * 224;

    bf16x8 ck0, ck1;
    uint2 v0lo, v0hi, v1lo, v1hi;
    ck0 = *(const bf16x8*)(kbase);
    ck1 = *(const bf16x8*)(kbase + 16 * 256);
    v0lo = *(const uint2*)(vb0 + 4 * lg);
    v0hi = *(const uint2*)(vb0 + 16 + 4 * lg);
    v1lo = *(const uint2*)(vb1 + 4 * lg);
    v1hi = *(const uint2*)(vb1 + 16 + 4 * lg);

    for (int ch = 0; ch < 7; ++ch) {
        int t0 = ch * 32;
        bf16x8 nk0, nk1;
        uint2 n0lo, n0hi, n1lo, n1hi;
        if (ch < 6) {   // T14: next chunk's fragments issued before compute
            int t0n = t0 + 32;
            nk0 = *(const bf16x8*)(kbase + (size_t)t0n * 256);
            nk1 = *(const bf16x8*)(kbase + (size_t)(t0n + 16) * 256);
            n0lo = *(const uint2*)(vb0 + t0n + 4 * lg);
            n0hi = *(const uint2*)(vb0 + t0n + 16 + 4 * lg);
            n1lo = *(const uint2*)(vb1 + t0n + 4 * lg);
            n1hi = *(const uint2*)(vb1 + t0n + 16 + 4 * lg);
            if (t0n == 192) {   // zero V slots with t>=196 (0 x stale hazard)
                uint2 zz = make_uint2(0u, 0u);
                n0hi = zz; n1hi = zz;                 // t >= 208
                if (lg) { n0lo = zz; n1lo = zz; }     // t = 192+4lg.. >= 196
            }
        }
        union { uint4 q; bf16x8 v; } u0, u1;
        u0.q = make_uint4(v0lo.x, v0lo.y, v0hi.x, v0hi.y);
        u1.q = make_uint4(v1lo.x, v1lo.y, v1hi.x, v1hi.y);
        bool mA[4], mB[4];
        #pragma unroll
        for (int r = 0; r < 4; ++r) {
            mA[r] = (t0 + 4 * lg + r)      >= 196;
            mB[r] = (t0 + 16 + 4 * lg + r) >= 196;
        }
        #pragma unroll
        for (int mt = 0; mt < 7; ++mt) {
            f32x4 z = {0.f,0.f,0.f,0.f};
            f32x4 s0 = MFMA(ck0, qf[mt], z);   // swapped: rows t, cols s
            f32x4 s1 = MFMA(ck1, qf[mt], z);
            float p00 = mA[0] ? 0.f : __expf(s0[0]);
            float p01 = mA[1] ? 0.f : __expf(s0[1]);
            float p02 = mA[2] ? 0.f : __expf(s0[2]);
            float p03 = mA[3] ? 0.f : __expf(s0[3]);
            float p10 = mB[0] ? 0.f : __expf(s1[0]);
            float p11 = mB[1] ? 0.f : __expf(s1[1]);
            float p12 = mB[2] ? 0.f : __expf(s1[2]);
            float p13 = mB[3] ? 0.f : __expf(s1[3]);
            union { uint4 q; bf16x8 v; } pu;
            pu.q.x = pk2(p00, p01);
            pu.q.y = pk2(p02, p03);
            pu.q.z = pk2(p10, p11);
            pu.q.w = pk2(p12, p13);
            o_acc[mt][0] = MFMA(pu.v, u0.v, o_acc[mt][0]);
            o_acc[mt][1] = MFMA(pu.v, u1.v, o_acc[mt][1]);
            l_acc[mt]    = MFMA(pu.v, ones, l_acc[mt]);
        }
        ck0 = nk0; ck1 = nk1;
        v0lo = n0lo; v0hi = n0hi; v1lo = n1lo; v1hi = n1hi;
    }

    // normalized O -> OB (wave-private columns)
    #pragma unroll
    for (int mt = 0; mt < 7; ++mt) {
        #pragma unroll
        for (int r = 0; r < 4; ++r) {
            float inv = 1.f / l_acc[mt][r];
            int srow = mt * 16 + lg * 4 + r;
            OB[srow * 264 + w * 32 + lr]      = f2bf(o_acc[mt][0][r] * inv);
            OB[srow * 264 + w * 32 + 16 + lr] = f2bf(o_acc[mt][1][r] * inv);
        }
    }
    __syncthreads();

    // oproj reads: a2 = OB @ wo_c^T
    f32x4 a2[7][2];
    #pragma unroll
    for (int mt = 0; mt < 7; ++mt) {
        f32x4 z = {0.f,0.f,0.f,0.f}; a2[mt][0] = z; a2[mt][1] = z;
    }
    for (int ks = 0; ks < 8; ++ks) {
        int c0 = ks * 32;
        bf16x8 bw0 = *(const bf16x8*)(Wall + (size_t)(1792 + w * 32 + lr) * 256 + c0 + lg * 8);
        bf16x8 bw1 = *(const bf16x8*)(Wall + (size_t)(1792 + w * 32 + 16 + lr) * 256 + c0 + lg * 8);
        #pragma unroll
        for (int mt = 0; mt < 7; ++mt) {
            bf16x8 afr = *(const bf16x8*)(&OB[(mt * 16 + lr) * 264 + c0 + lg * 8]);
            a2[mt][0] = MFMA(afr, bw0, a2[mt][0]);
            a2[mt][1] = MFMA(afr, bw1, a2[mt][1]);
        }
    }
    __syncthreads();   // all O reads done; overwrite with O2

    {
        float biasA = Ball[1792 + w * 32 + lr];
        float biasB = Ball[1792 + w * 32 + 16 + lr];
        #pragma unroll
        for (int mt = 0; mt < 7; ++mt)
            #pragma unroll
            for (int r = 0; r < 4; ++r) {
                int srow = mt * 16 + lg * 4 + r;
                OB[srow * 264 + w * 32 + lr]      = f2bf(a2[mt][0][r] + biasA);
                OB[srow * 264 + w * 32 + 16 + lr] = f2bf(a2[mt][1][r] + biasB);
            }
    }
    __syncthreads();   // O2 in OB

    // h1 reads (a2 reused) + score head from O2
    #pragma unroll
    for (int mt = 0; mt < 7; ++mt) {
        f32x4 z = {0.f,0.f,0.f,0.f}; a2[mt][0] = z; a2[mt][1] = z;
    }
    for (int ks = 0; ks < 8; ++ks) {
        int c0 = ks * 32;
        bf16x8 bw0 = *(const bf16x8*)(Wall + (size_t)(2048 + w * 32 + lr) * 256 + c0 + lg * 8);
        bf16x8 bw1 = *(const bf16x8*)(Wall + (size_t)(2048 + w * 32 + 16 + lr) * 256 + c0 + lg * 8);
        #pragma unroll
        for (int mt = 0; mt < 7; ++mt) {
            bf16x8 afr = *(const bf16x8*)(&OB[(mt * 16 + lr) * 264 + c0 + lg * 8]);
            a2[mt][0] = MFMA(afr, bw0, a2[mt][0]);
            a2[mt][1] = MFMA(afr, bw1, a2[mt][1]);
        }
    }
    if (tid < 100) {
        float s = 0.f;
        for (int c2 = 0; c2 < 256; ++c2)
            s += bf2f(OB[tid * 264 + c2]) * bf2f(Wall[(size_t)2336 * 256 + c2]);
        s += Ball[2336];
        scb[tid] = 1.f / (1.f + __expf(-s));
    }
    __syncthreads();   // all O2 reads done; overwrite with h1

    {
        float biasA = Ball[2048 + w * 32 + lr];
        float biasB = Ball[2048 + w * 32 + 16 + lr];
        #pragma unroll
        for (int mt = 0; mt < 7; ++mt)
            #pragma unroll
            for (int r = 0; r < 4; ++r) {
                int srow = mt * 16 + lg * 4 + r;
                float vA = a2[mt][0][r] + biasA;
                float vB = a2[mt][1][r] + biasB;
                vA = vA > 0.f ? vA : 0.f;
                vB = vB > 0.f ? vB : 0.f;
                OB[srow * 264 + w * 32 + lr]      = f2bf(vA);
                OB[srow * 264 + w * 32 + 16 + lr] = f2bf(vB);
            }
    }
    __syncthreads();   // h1 in OB

    if (tid < 256) {
        float s = 0.f;
        for (int srow = 0; srow < 100; ++srow) s += bf2f(OB[srow * 264 + tid]);
        hbar[tid] = s * 0.01f;
    }
    __syncthreads();
    if (tid < 32) {
        float s = 0.f;
        for (int c2 = 0; c2 < 256; ++c2)
            s += hbar[c2] * bf2f(Wall[(size_t)(2304 + tid) * 256 + c2]);
        s += Ball[2304 + tid];
        outp[(size_t)n * 32 + tid] = s;
    }
    if (tid == 64) {
        float s = 0.f;
        for (int i2 = 0; i2 < 100; ++i2) s += scb[i2];
        outp[16384 + n] = s * 0.01f;
    }
}

// ---------------------------------------------------------------------------
extern "C" void kernel_launch(void* const* d_in, const int* in_sizes, int n_in,
                              void* d_out, int out_size, void* d_ws, size_t ws_size,
                              hipStream_t stream)
{
    const float* features = (const float*)d_in[0];
    const float* qfeat    = (const float*)d_in[1];
    char* ws = (char*)d_ws;

    ushort* wbf  = (ushort*)ws;                    //  2337*256 bf16
    float*  bias = (float*)(ws + 1196544);         //  2337 f32
    ushort* qkv  = (ushort*)(ws + 1206016);        //  800*768
    ushort* sav  = (ushort*)(ws + 2434816);        //  800*256
    ushort* osb  = (ushort*)(ws + 2844416);        //  800*256
    ushort* qcp  = (ushort*)(ws + 3254016);        //  8*8*112*32
    ushort* kvb  = (ushort*)(ws + 3712768);

    prep_kernel<<<dim3(512), dim3(256), 0, stream>>>(
        (const float*)d_in[2], (const float*)d_in[3], (const float*)d_in[4],
        (const float*)d_in[8], (const float*)d_in[10], (const float*)d_in[11],
        (const float*)d_in[12], (const float*)d_in[16], (const float*)d_in[18],
        (const float*)d_in[20], (const float*)d_in[22],
        (const float*)d_in[5], (const float*)d_in[6], (const float*)d_in[7],
        (const float*)d_in[9], (const float*)d_in[13], (const float*)d_in[14],
        (const float*)d_in[15], (const float*)d_in[17], (const float*)d_in[19],
        (const float*)d_in[21], (const float*)d_in[23],
        wbf, bias, qcp);

    // self-attention chain
    gemm_rows<1, 100, 0><<<dim3(13, 6), dim3(256), 0, stream>>>(
        qfeat, wbf, bias, qkv, 800, 0, 0, 768);
    self_attn<<<dim3(64), dim3(128), 0, stream>>>(qkv, sav);
    gemm_rows<0, 1, 0><<<dim3(13, 2), dim3(256), 0, stream>>>(
        sav, wbf, bias, osb, 800, 768, 768, 256);
    gemm_rows<0, 1, 1><<<dim3(13, 2), dim3(256), 0, stream>>>(
        osb, wbf, bias, qcp, 800, 1024, 1024, 0);

    // cross-attention, pass-split on workspace budget
    const size_t per_n = 229376;               // bytes of kc+vc per proposal
    long avail = (long)ws_size - 3712768L;
    int Np = 512;
    if (avail < (long)(per_n * 512)) {
        Np = (int)(avail / (long)per_n);
        if (Np < 1) Np = 1;
    }
    ushort* kcb = kvb;                                   // [Np][224][256]
    ushort* vcb = kvb + (size_t)Np * 224 * 256;          // [Np][256][224]
    float* outp = (float*)d_out;
    for (int n0 = 0; n0 < 512; n0 += Np) {
        int cnt = (512 - n0 < Np) ? (512 - n0) : Np;
        kvproj<<<dim3(cnt), dim3(512), 0, stream>>>(features, wbf, bias, kcb, vcb, n0);
        attn_fuse<<<dim3(cnt), dim3(512), 0, stream>>>(qcp, kcb, vcb, wbf, bias, outp, n0);
    }
}

// Round 17
// 211.121 us; speedup vs baseline: 1.1674x; 1.1674x over previous
//
#include <hip/hip_runtime.h>
#include <hip/hip_bf16.h>

// ---------------------------------------------------------------------------
// PolygonPredictionLayer: B=8,P=64,N=512,T=196(->224),S=100(->112),C=256,H=8,dh=32
// R16: bank R13 (207us) + additive wins only.
//   - attn_fuse v7 = R13 v4 (512,2) + depth-2 K/V register prefetch (3 rotating
//     sets, ch-loop fully unrolled -> static indices) + s_setprio around compute.
//   - G2+G3 folded: qcp = sav @ M^T + b', M = wq_c@wo_s, b' = bq_c + wq_c@bo_s
//     (wcomb kernel overwrites wbf rows 1024..1279 / bias[1024..1279]).
//   - kvproj v9 unchanged.
// ---------------------------------------------------------------------------

typedef __attribute__((ext_vector_type(8))) short bf16x8;
typedef __attribute__((ext_vector_type(4))) float f32x4;

__device__ __forceinline__ float bf2f(ushort u) {
    union { float f; uint u32; } v; v.u32 = ((uint)u) << 16; return v.f;
}
__device__ __forceinline__ ushort f2bf(float f) {
    union { float f; uint u; } v; v.f = f;
    uint r = v.u + 0x7FFF + ((v.u >> 16) & 1);
    return (ushort)(r >> 16);
}
__device__ __forceinline__ uint pk2(float a, float b) {
    __hip_bfloat162 h = __float22bfloat162_rn(make_float2(a, b));
    union { __hip_bfloat162 h2; uint u; } c; c.h2 = h; return c.u;
}
__device__ __forceinline__ f32x4 MFMA(bf16x8 a, bf16x8 b, f32x4 c) {
    return __builtin_amdgcn_mfma_f32_16x16x32_bf16(a, b, c, 0, 0, 0);
}

#define SCALE_DH 0.17677669529663687f  // 1/sqrt(32)

// ---------------- prep: weights+biases -> ws tables, qcp zero ---------------
#define TOTALW (2337 * 256)
#define QCPN   (8 * 8 * 112 * 32)
#define NBIAS  2337

__global__ void prep_kernel(const float* w0, const float* w1_, const float* w2_,
                            const float* w3, const float* w4, const float* w5,
                            const float* w6, const float* w7, const float* w8,
                            const float* w9, const float* w10,
                            const float* b0, const float* b1_, const float* b2_,
                            const float* b3, const float* b4, const float* b5,
                            const float* b6, const float* b7, const float* b8,
                            const float* b9, const float* b10,
                            ushort* wbf, float* bias, ushort* qcp)
{
    for (size_t i = blockIdx.x * blockDim.x + threadIdx.x;
         i < (size_t)TOTALW + QCPN + NBIAS; i += (size_t)gridDim.x * blockDim.x) {
        if (i < TOTALW) {
            int row = (int)(i >> 8), col = (int)(i & 255);
            const float* sp; int base;
            if      (row < 256)  { sp = w0;  base = 0; }
            else if (row < 512)  { sp = w1_; base = 256; }
            else if (row < 768)  { sp = w2_; base = 512; }
            else if (row < 1024) { sp = w3;  base = 768; }
            else if (row < 1280) { sp = w4;  base = 1024; }
            else if (row < 1536) { sp = w5;  base = 1280; }
            else if (row < 1792) { sp = w6;  base = 1536; }
            else if (row < 2048) { sp = w7;  base = 1792; }
            else if (row < 2304) { sp = w8;  base = 2048; }
            else if (row < 2336) { sp = w9;  base = 2304; }
            else                 { sp = w10; base = 2336; }
            wbf[i] = f2bf(sp[(size_t)(row - base) * 256 + col]);
        } else if (i < (size_t)TOTALW + QCPN) {
            qcp[i - TOTALW] = 0;
        } else {
            int idx = (int)(i - TOTALW - QCPN);
            const float* sp; int base;
            if      (idx < 256)  { sp = b0;  base = 0; }
            else if (idx < 512)  { sp = b1_; base = 256; }
            else if (idx < 768)  { sp = b2_; base = 512; }
            else if (idx < 1024) { sp = b3;  base = 768; }
            else if (idx < 1280) { sp = b4;  base = 1024; }
            else if (idx < 1536) { sp = b5;  base = 1280; }
            else if (idx < 1792) { sp = b6;  base = 1536; }
            else if (idx < 2048) { sp = b7;  base = 1792; }
            else if (idx < 2304) { sp = b8;  base = 2048; }
            else if (idx < 2336) { sp = b9;  base = 2304; }
            else                 { sp = b10; base = 2336; }
            bias[idx] = sp[idx - base];
        }
    }
}

// ---------------- wcomb: M = wq_c @ wo_s -> wbf rows 1024..1279 -------------
// b' = bq_c + wq_c @ bo_s -> bias[1024..1279]. Runs after prep (overwrites).
__global__ __launch_bounds__(256)
void wcomb(const float* wq_c, const float* wo_s, const float* bq_c,
           const float* bo_s, ushort* wbf, float* bias)
{
    __shared__ float row[256];
    int i = blockIdx.x, k = threadIdx.x;
    row[k] = wq_c[(size_t)i * 256 + k];
    __syncthreads();
    float acc = 0.f;
    for (int j = 0; j < 256; ++j)
        acc = fmaf(row[j], wo_s[(size_t)j * 256 + k], acc);
    wbf[(size_t)(1024 + i) * 256 + k] = f2bf(acc);
    if (k == 0) {
        float s = bq_c[i];
        for (int j = 0; j < 256; ++j) s += row[j] * bo_s[j];
        bias[1024 + i] = s;
    }
}

// ---------------- generic small GEMM: out = A @ W^T + bias -----------------
template<int ASRC, int GS, int EPI>
__global__ __launch_bounds__(256)
void gemm_rows(const void* Aptr, const ushort* Wall, const float* Ball,
               ushort* Out, int M, int Wrow0, int Brow0, int ldo)
{
    __shared__ ushort As[64 * 40];
    __shared__ ushort Bs[128 * 40];
    int tid = threadIdx.x;
    int lane = tid & 63, w = tid >> 6;
    int lr = lane & 15, lg = lane >> 4;
    int r0 = blockIdx.x * 64;
    int j0 = blockIdx.y * 128;

    f32x4 acc[4][2];
    #pragma unroll
    for (int mt = 0; mt < 4; ++mt)
        #pragma unroll
        for (int nt = 0; nt < 2; ++nt) { f32x4 z = {0.f,0.f,0.f,0.f}; acc[mt][nt] = z; }

    for (int ks = 0; ks < 8; ++ks) {
        int c0 = ks * 32;
        {
            int i = tid >> 2, q = tid & 3;
            int r = r0 + i;
            if (ASRC == 0) {
                uint4 v = make_uint4(0u,0u,0u,0u);
                if (r < M) v = *(const uint4*)((const ushort*)Aptr + (size_t)r * 256 + c0 + q * 8);
                *(uint4*)(&As[i * 40 + q * 8]) = v;
            } else {
                uint u[4] = {0u,0u,0u,0u};
                if (r < M) {
                    int g = r / GS, o = r - g * GS;
                    const float* src = (const float*)Aptr + (size_t)g * 256 * GS + o;
                    #pragma unroll
                    for (int k2 = 0; k2 < 4; ++k2) {
                        ushort a0 = f2bf(src[(size_t)(c0 + q * 8 + 2 * k2)     * GS]);
                        ushort a1 = f2bf(src[(size_t)(c0 + q * 8 + 2 * k2 + 1) * GS]);
                        u[k2] = (uint)a0 | ((uint)a1 << 16);
                    }
                }
                *(uint4*)(&As[i * 40 + q * 8]) = make_uint4(u[0], u[1], u[2], u[3]);
            }
        }
        {
            int jj = tid >> 1, half = tid & 1;
            const ushort* src = Wall + (size_t)(Wrow0 + j0 + jj) * 256 + c0 + half * 16;
            ushort* dst = &Bs[jj * 40 + half * 16];
            *(uint4*)(dst)     = *(const uint4*)(src);
            *(uint4*)(dst + 8) = *(const uint4*)(src + 8);
        }
        __syncthreads();
        bf16x8 bfr[2];
        #pragma unroll
        for (int nt = 0; nt < 2; ++nt)
            bfr[nt] = *(const bf16x8*)(&Bs[(w * 32 + nt * 16 + lr) * 40 + lg * 8]);
        #pragma unroll
        for (int mt = 0; mt < 4; ++mt) {
            bf16x8 afr = *(const bf16x8*)(&As[(mt * 16 + lr) * 40 + lg * 8]);
            acc[mt][0] = MFMA(afr, bfr[0], acc[mt][0]);
            acc[mt][1] = MFMA(afr, bfr[1], acc[mt][1]);
        }
        __syncthreads();
    }
    #pragma unroll
    for (int mt = 0; mt < 4; ++mt) {
        #pragma unroll
        for (int nt = 0; nt < 2; ++nt) {
            int jc = j0 + w * 32 + nt * 16 + lr;
            float bias = Ball[Brow0 + jc];
            #pragma unroll
            for (int rg = 0; rg < 4; ++rg) {
                int r = r0 + mt * 16 + lg * 4 + rg;
                if (r >= M) continue;
                float vv = acc[mt][nt][rg] + bias;
                if (EPI == 0) {
                    Out[(size_t)r * ldo + jc] = f2bf(vv);
                } else {
                    int b = r / 100, s = r - b * 100;
                    int h = jc >> 5, d = jc & 31;
                    Out[(((size_t)(b * 8 + h)) * 112 + s) * 32 + d] = f2bf(vv * SCALE_DH);
                }
            }
        }
    }
}

// ---------------- self-attention (tiny, VALU) ------------------------------
__global__ __launch_bounds__(128)
void self_attn(const ushort* qkv, ushort* sav)
{
    __shared__ float kls[100][33];
    __shared__ float vls[100][33];
    __shared__ float sls[100][101];
    int bh = blockIdx.x; int b = bh >> 3, h = bh & 7;
    int tid = threadIdx.x;
    for (int idx = tid; idx < 100 * 32; idx += 128) {
        int t = idx >> 5, d = idx & 31;
        kls[t][d] = bf2f(qkv[((size_t)(b * 100 + t)) * 768 + 256 + h * 32 + d]);
        vls[t][d] = bf2f(qkv[((size_t)(b * 100 + t)) * 768 + 512 + h * 32 + d]);
    }
    __syncthreads();
    if (tid < 100) {
        int s = tid;
        float q[32];
        #pragma unroll
        for (int d = 0; d < 32; ++d)
            q[d] = bf2f(qkv[((size_t)(b * 100 + s)) * 768 + h * 32 + d]) * SCALE_DH;
        float mx = -1e30f;
        for (int t = 0; t < 100; ++t) {
            float sc = 0.f;
            #pragma unroll
            for (int d = 0; d < 32; ++d) sc += q[d] * kls[t][d];
            sls[s][t] = sc; mx = fmaxf(mx, sc);
        }
        float sum = 0.f;
        for (int t = 0; t < 100; ++t) {
            float p = __expf(sls[s][t] - mx);
            sls[s][t] = p; sum += p;
        }
        float inv = 1.f / sum;
        float acc2[32];
        #pragma unroll
        for (int d = 0; d < 32; ++d) acc2[d] = 0.f;
        for (int t = 0; t < 100; ++t) {
            float pv = sls[s][t];
            #pragma unroll
            for (int d = 0; d < 32; ++d) acc2[d] += pv * vls[t][d];
        }
        #pragma unroll
        for (int d = 0; d < 32; ++d)
            sav[((size_t)(b * 100 + s)) * 256 + h * 32 + d] = f2bf(acc2[d] * inv);
    }
}

// ---------------- kvproj v9: kc[n][224][256] t-major, vc[n][256][224] ------
// One block per proposal, block 512 (8 waves), LDS featT[224][264] bf16.
// Weights persistent af[4][8]. pk2/uint2 staging. Pad skipped (13 tiles).
__global__ __launch_bounds__(512, 2)
void kvproj(const float* features, const ushort* Wall, const float* Ball,
            ushort* kc, ushort* vc, int n_base)
{
    __shared__ ushort featT[224 * 264];
    int tid = threadIdx.x;
    int lane = tid & 63, w = tid >> 6;
    int lr = lane & 15, lg = lane >> 4;
    int nl = blockIdx.x;
    int n  = n_base + nl;
    const float* fb = features + (size_t)n * 256 * 196;

    bf16x8 af[4][8];
    #pragma unroll
    for (int m = 0; m < 4; ++m) {
        int row = ((m < 2) ? 1280 : 1536) + w * 32 + (m & 1) * 16 + lr;
        #pragma unroll
        for (int ks = 0; ks < 8; ++ks)
            af[m][ks] = *(const bf16x8*)(Wall + (size_t)row * 256 + ks * 32 + lg * 8);
    }
    float biask0 = Ball[1280 + w * 32 + lr];
    float biask1 = Ball[1296 + w * 32 + lr];
    float biasv0 = Ball[1536 + w * 32 + lr];
    float biasv1 = Ball[1552 + w * 32 + lr];

    #pragma unroll
    for (int it = 0; it < 7; ++it) {
        int idx = tid + it * 512;
        if (idx < 3136) {
            int cg = idx / 49, tq = idx - cg * 49;
            const float* p = fb + (size_t)(cg * 4) * 196 + tq * 4;
            float4 v0 = *(const float4*)(p);
            float4 v1 = *(const float4*)(p + 196);
            float4 v2 = *(const float4*)(p + 392);
            float4 v3 = *(const float4*)(p + 588);
            #pragma unroll
            for (int j = 0; j < 4; ++j) {
                float e0 = (j == 0) ? v0.x : (j == 1) ? v0.y : (j == 2) ? v0.z : v0.w;
                float e1 = (j == 0) ? v1.x : (j == 1) ? v1.y : (j == 2) ? v1.z : v1.w;
                float e2 = (j == 0) ? v2.x : (j == 1) ? v2.y : (j == 2) ? v2.z : v2.w;
                float e3 = (j == 0) ? v3.x : (j == 1) ? v3.y : (j == 2) ? v3.z : v3.w;
                uint2 pr;
                pr.x = pk2(e0, e1);
                pr.y = pk2(e2, e3);
                *(uint2*)(&featT[(tq * 4 + j) * 264 + cg * 4]) = pr;
            }
        }
    }
    for (int idx = tid; idx < 12 * 264; idx += 512)
        featT[196 * 264 + idx] = 0;
    __syncthreads();   // the only barrier

    for (int tt = 0; tt < 13; ++tt) {
        bf16x8 a8[8];
        #pragma unroll
        for (int ks = 0; ks < 8; ++ks)
            a8[ks] = *(const bf16x8*)(&featT[(tt * 16 + lr) * 264 + ks * 32 + lg * 8]);
        f32x4 acc[4];
        #pragma unroll
        for (int m = 0; m < 4; ++m) { f32x4 z = {0.f,0.f,0.f,0.f}; acc[m] = z; }
        #pragma unroll
        for (int ks = 0; ks < 8; ++ks)
            #pragma unroll
            for (int m = 0; m < 4; ++m)
                acc[m] = MFMA(a8[ks], af[m][ks], acc[m]);

        int tb = tt * 16 + lg * 4;
        #pragma unroll
        for (int rg = 0; rg < 4; ++rg) {
            int t = tb + rg;
            if (t < 196) {
                kc[((size_t)nl * 224 + t) * 256 + w * 32 + lr]      = f2bf(acc[0][rg] + biask0);
                kc[((size_t)nl * 224 + t) * 256 + w * 32 + 16 + lr] = f2bf(acc[1][rg] + biask1);
            }
        }
        if (tb < 196) {
            size_t vb0 = ((size_t)nl * 256 + w * 32 + lr) * 224 + tb;
            size_t vb1 = ((size_t)nl * 256 + w * 32 + 16 + lr) * 224 + tb;
            uint a01 = pk2(acc[2][0] + biasv0, acc[2][1] + biasv0);
            uint a23 = pk2(acc[2][2] + biasv0, acc[2][3] + biasv0);
            uint b01 = pk2(acc[3][0] + biasv1, acc[3][1] + biasv1);
            uint b23 = pk2(acc[3][2] + biasv1, acc[3][3] + biasv1);
            *(uint*)(vc + vb0)     = a01;
            *(uint*)(vc + vb0 + 2) = a23;
            *(uint*)(vc + vb1)     = b01;
            *(uint*)(vc + vb1 + 2) = b23;
        }
    }
}

// ---------------- attn_fuse v7: swapped QK^T + depth-2 prefetch ------------
// block 512 (8 waves, wave = head), (512,2). Main loop zero-LDS (R13); K/V
// fragments double-prefetched (3 rotating register sets, ch-loop unrolled).
// s_setprio(1) around the compute cluster. Epilogue = R13 (OL/O2 overlay).
__global__ __launch_bounds__(512, 2)
void attn_fuse(const ushort* qcp, const ushort* kc, const ushort* vc,
               const ushort* Wall, const float* Ball, float* outp, int n_base)
{
    __shared__ char smem[130816];
    ushort* OL  = (ushort*)smem;
    float* hbar = (float*)(smem + 59392);
    float* scb  = (float*)(smem + 60416);
    ushort* O2  = (ushort*)(smem + 71680);

    int tid = threadIdx.x;
    int lane = tid & 63; int w = tid >> 6;             // w = head
    int lr = lane & 15, lg = lane >> 4;
    int nl = blockIdx.x; int n = n_base + nl;
    int b = n >> 6;
    const ushort* kcn = kc + (size_t)nl * 224 * 256;
    const ushort* vcn = vc + (size_t)nl * 256 * 224;

    bf16x8 qf[7];
    #pragma unroll
    for (int mt = 0; mt < 7; ++mt)
        qf[mt] = *(const bf16x8*)(qcp + ((((size_t)(b * 8 + w)) * 112 + mt * 16 + lr) * 32 + lg * 8));

    bf16x8 ones;
    #pragma unroll
    for (int j = 0; j < 8; ++j) ones[j] = (short)0x3F80;

    f32x4 o_acc[7][2], l_acc[7];
    #pragma unroll
    for (int mt = 0; mt < 7; ++mt) {
        f32x4 z = {0.f,0.f,0.f,0.f};
        o_acc[mt][0] = z; o_acc[mt][1] = z; l_acc[mt] = z;
    }

    const ushort* kbase = kcn + (size_t)lr * 256 + w * 32 + lg * 8;
    const ushort* vrow0 = vcn + ((size_t)(w * 32 + lr)) * 224;
    const ushort* vrow1 = vcn + ((size_t)(w * 32 + 16 + lr)) * 224;

    bf16x8 k0[3], k1[3];
    uint2 va[3], vb[3], vcq[3], vd[3];
    #pragma unroll
    for (int pc = 0; pc < 2; ++pc) {
        int t0n = pc * 32;
        k0[pc] = *(const bf16x8*)(kbase + (size_t)t0n * 256);
        k1[pc] = *(const bf16x8*)(kbase + (size_t)(t0n + 16) * 256);
        va[pc]  = *(const uint2*)(vrow0 + t0n + 4 * lg);
        vb[pc]  = *(const uint2*)(vrow0 + t0n + 16 + 4 * lg);
        vcq[pc] = *(const uint2*)(vrow1 + t0n + 4 * lg);
        vd[pc]  = *(const uint2*)(vrow1 + t0n + 16 + 4 * lg);
    }

    #pragma unroll
    for (int ch = 0; ch < 7; ++ch) {
        const int cur = ch % 3;
        int t0 = ch * 32;
        if (ch + 2 < 7) {   // T14 depth-2: issue loads 2 chunks ahead
            const int nx = (ch + 2) % 3;
            int t0n = (ch + 2) * 32;
            k0[nx] = *(const bf16x8*)(kbase + (size_t)t0n * 256);
            k1[nx] = *(const bf16x8*)(kbase + (size_t)(t0n + 16) * 256);
            va[nx]  = *(const uint2*)(vrow0 + t0n + 4 * lg);
            vb[nx]  = *(const uint2*)(vrow0 + t0n + 16 + 4 * lg);
            vcq[nx] = *(const uint2*)(vrow1 + t0n + 4 * lg);
            vd[nx]  = *(const uint2*)(vrow1 + t0n + 16 + 4 * lg);
            if (t0n == 192) {   // zero V slots with t>=196 (0 x stale hazard)
                uint2 zz = make_uint2(0u, 0u);
                vb[nx] = zz; vd[nx] = zz;                 // t >= 208
                if (lg) { va[nx] = zz; vcq[nx] = zz; }    // t = 192+4lg.. >= 196
            }
        }
        union { uint4 q; bf16x8 v; } u0, u1;
        u0.q = make_uint4(va[cur].x, va[cur].y, vb[cur].x, vb[cur].y);
        u1.q = make_uint4(vcq[cur].x, vcq[cur].y, vd[cur].x, vd[cur].y);
        bool mA[4], mB[4];
        #pragma unroll
        for (int r = 0; r < 4; ++r) {
            mA[r] = (t0 + 4 * lg + r)      >= 196;
            mB[r] = (t0 + 16 + 4 * lg + r) >= 196;
        }
        __builtin_amdgcn_s_setprio(1);
        #pragma unroll
        for (int mt = 0; mt < 7; ++mt) {
            f32x4 z = {0.f,0.f,0.f,0.f};
            f32x4 s0 = MFMA(k0[cur], qf[mt], z);   // swapped: rows t, cols s
            f32x4 s1 = MFMA(k1[cur], qf[mt], z);
            float p00 = mA[0] ? 0.f : __expf(s0[0]);
            float p01 = mA[1] ? 0.f : __expf(s0[1]);
            float p02 = mA[2] ? 0.f : __expf(s0[2]);
            float p03 = mA[3] ? 0.f : __expf(s0[3]);
            float p10 = mB[0] ? 0.f : __expf(s1[0]);
            float p11 = mB[1] ? 0.f : __expf(s1[1]);
            float p12 = mB[2] ? 0.f : __expf(s1[2]);
            float p13 = mB[3] ? 0.f : __expf(s1[3]);
            union { uint4 q; bf16x8 v; } pu;
            pu.q.x = pk2(p00, p01);
            pu.q.y = pk2(p02, p03);
            pu.q.z = pk2(p10, p11);
            pu.q.w = pk2(p12, p13);
            o_acc[mt][0] = MFMA(pu.v, u0.v, o_acc[mt][0]);
            o_acc[mt][1] = MFMA(pu.v, u1.v, o_acc[mt][1]);
            l_acc[mt]    = MFMA(pu.v, ones, l_acc[mt]);
        }
        __builtin_amdgcn_s_setprio(0);
    }

    // normalized O -> OL[112][264] (wave-private columns)
    #pragma unroll
    for (int mt = 0; mt < 7; ++mt) {
        #pragma unroll
        for (int r = 0; r < 4; ++r) {
            float inv = 1.f / l_acc[mt][r];
            int srow = mt * 16 + lg * 4 + r;
            OL[srow * 264 + w * 32 + lr]      = f2bf(o_acc[mt][0][r] * inv);
            OL[srow * 264 + w * 32 + 16 + lr] = f2bf(o_acc[mt][1][r] * inv);
        }
    }
    __syncthreads();

    // o2 = OL @ wo_c^T + bo_c
    {
        f32x4 a2[7][2];
        #pragma unroll
        for (int mt = 0; mt < 7; ++mt) {
            f32x4 z = {0.f,0.f,0.f,0.f}; a2[mt][0] = z; a2[mt][1] = z;
        }
        for (int ks = 0; ks < 8; ++ks) {
            int c0 = ks * 32;
            bf16x8 bw0 = *(const bf16x8*)(Wall + (size_t)(1792 + w * 32 + lr) * 256 + c0 + lg * 8);
            bf16x8 bw1 = *(const bf16x8*)(Wall + (size_t)(1792 + w * 32 + 16 + lr) * 256 + c0 + lg * 8);
            #pragma unroll
            for (int mt = 0; mt < 7; ++mt) {
                bf16x8 afr = *(const bf16x8*)(&OL[(mt * 16 + lr) * 264 + c0 + lg * 8]);
                a2[mt][0] = MFMA(afr, bw0, a2[mt][0]);
                a2[mt][1] = MFMA(afr, bw1, a2[mt][1]);
            }
        }
        float biasA = Ball[1792 + w * 32 + lr];
        float biasB = Ball[1792 + w * 32 + 16 + lr];
        #pragma unroll
        for (int mt = 0; mt < 7; ++mt)
            #pragma unroll
            for (int r = 0; r < 4; ++r) {
                int srow = mt * 16 + lg * 4 + r;
                O2[srow * 264 + w * 32 + lr]      = f2bf(a2[mt][0][r] + biasA);
                O2[srow * 264 + w * 32 + 16 + lr] = f2bf(a2[mt][1][r] + biasB);
            }
    }
    __syncthreads();

    // h1 = relu(O2 @ w1^T + b1) -> OL
    {
        f32x4 a2[7][2];
        #pragma unroll
        for (int mt = 0; mt < 7; ++mt) {
            f32x4 z = {0.f,0.f,0.f,0.f}; a2[mt][0] = z; a2[mt][1] = z;
        }
        for (int ks = 0; ks < 8; ++ks) {
            int c0 = ks * 32;
            bf16x8 bw0 = *(const bf16x8*)(Wall + (size_t)(2048 + w * 32 + lr) * 256 + c0 + lg * 8);
            bf16x8 bw1 = *(const bf16x8*)(Wall + (size_t)(2048 + w * 32 + 16 + lr) * 256 + c0 + lg * 8);
            #pragma unroll
            for (int mt = 0; mt < 7; ++mt) {
                bf16x8 afr = *(const bf16x8*)(&O2[(mt * 16 + lr) * 264 + c0 + lg * 8]);
                a2[mt][0] = MFMA(afr, bw0, a2[mt][0]);
                a2[mt][1] = MFMA(afr, bw1, a2[mt][1]);
            }
        }
        __syncthreads();   // OL (oproj source) reads finished before overwrite
        float biasA = Ball[2048 + w * 32 + lr];
        float biasB = Ball[2048 + w * 32 + 16 + lr];
        #pragma unroll
        for (int mt = 0; mt < 7; ++mt)
            #pragma unroll
            for (int r = 0; r < 4; ++r) {
                int srow = mt * 16 + lg * 4 + r;
                float vA = a2[mt][0][r] + biasA;
                float vB = a2[mt][1][r] + biasB;
                vA = vA > 0.f ? vA : 0.f;
                vB = vB > 0.f ? vB : 0.f;
                OL[srow * 264 + w * 32 + lr]      = f2bf(vA);
                OL[srow * 264 + w * 32 + 16 + lr] = f2bf(vB);
            }
    }
    __syncthreads();

    // hbar[c] = mean_s<100 h1[s][c];  score partials from O2
    if (tid < 256) {
        float s = 0.f;
        for (int srow = 0; srow < 100; ++srow) s += bf2f(OL[srow * 264 + tid]);
        hbar[tid] = s * 0.01f;
    }
    if (tid < 100) {
        float s = 0.f;
        for (int c2 = 0; c2 < 256; ++c2)
            s += bf2f(O2[tid * 264 + c2]) * bf2f(Wall[(size_t)2336 * 256 + c2]);
        s += Ball[2336];
        scb[tid] = 1.f / (1.f + __expf(-s));
    }
    __syncthreads();
    if (tid < 32) {
        float s = 0.f;
        for (int c2 = 0; c2 < 256; ++c2)
            s += hbar[c2] * bf2f(Wall[(size_t)(2304 + tid) * 256 + c2]);
        s += Ball[2304 + tid];
        outp[(size_t)n * 32 + tid] = s;
    }
    if (tid == 64) {
        float s = 0.f;
        for (int i2 = 0; i2 < 100; ++i2) s += scb[i2];
        outp[16384 + n] = s * 0.01f;
    }
}

// ---------------------------------------------------------------------------
extern "C" void kernel_launch(void* const* d_in, const int* in_sizes, int n_in,
                              void* d_out, int out_size, void* d_ws, size_t ws_size,
                              hipStream_t stream)
{
    const float* features = (const float*)d_in[0];
    const float* qfeat    = (const float*)d_in[1];
    char* ws = (char*)d_ws;

    ushort* wbf  = (ushort*)ws;                    //  2337*256 bf16
    float*  bias = (float*)(ws + 1196544);         //  2337 f32
    ushort* qkv  = (ushort*)(ws + 1206016);        //  800*768
    ushort* sav  = (ushort*)(ws + 2434816);        //  800*256
    ushort* qcp  = (ushort*)(ws + 3254016);        //  8*8*112*32
    ushort* kvb  = (ushort*)(ws + 3712768);

    prep_kernel<<<dim3(512), dim3(256), 0, stream>>>(
        (const float*)d_in[2], (const float*)d_in[3], (const float*)d_in[4],
        (const float*)d_in[8], (const float*)d_in[10], (const float*)d_in[11],
        (const float*)d_in[12], (const float*)d_in[16], (const float*)d_in[18],
        (const float*)d_in[20], (const float*)d_in[22],
        (const float*)d_in[5], (const float*)d_in[6], (const float*)d_in[7],
        (const float*)d_in[9], (const float*)d_in[13], (const float*)d_in[14],
        (const float*)d_in[15], (const float*)d_in[17], (const float*)d_in[19],
        (const float*)d_in[21], (const float*)d_in[23],
        wbf, bias, qcp);

    // fold wq_c @ wo_s into M (overwrites wbf rows 1024..1279 / bias 1024..)
    wcomb<<<dim3(256), dim3(256), 0, stream>>>(
        (const float*)d_in[10], (const float*)d_in[8],
        (const float*)d_in[13], (const float*)d_in[9], wbf, bias);

    // self-attention chain (G2+G3 folded into one GEMM via M)
    gemm_rows<1, 100, 0><<<dim3(13, 6), dim3(256), 0, stream>>>(
        qfeat, wbf, bias, qkv, 800, 0, 0, 768);
    self_attn<<<dim3(64), dim3(128), 0, stream>>>(qkv, sav);
    gemm_rows<0, 1, 1><<<dim3(13, 2), dim3(256), 0, stream>>>(
        sav, wbf, bias, qcp, 800, 1024, 1024, 0);

    // cross-attention, pass-split on workspace budget
    const size_t per_n = 229376;               // bytes of kc+vc per proposal
    long avail = (long)ws_size - 3712768L;
    int Np = 512;
    if (avail < (long)(per_n * 512)) {
        Np = (int)(avail / (long)per_n);
        if (Np < 1) Np = 1;
    }
    ushort* kcb = kvb;                                   // [Np][224][256]
    ushort* vcb = kvb + (size_t)Np * 224 * 256;          // [Np][256][224]
    float* outp = (float*)d_out;
    for (int n0 = 0; n0 < 512; n0 += Np) {
        int cnt = (512 - n0 < Np) ? (512 - n0) : Np;
        kvproj<<<dim3(cnt), dim3(512), 0, stream>>>(features, wbf, bias, kcb, vcb, n0);
        attn_fuse<<<dim3(cnt), dim3(512), 0, stream>>>(qcp, kcb, vcb, wbf, bias, outp, n0);
    }
}

// Round 18
// 199.804 us; speedup vs baseline: 1.2335x; 1.0566x over previous
//
#include <hip/hip_runtime.h>
#include <hip/hip_bf16.h>

// ---------------------------------------------------------------------------
// PolygonPredictionLayer: B=8,P=64,N=512,T=196(->224),S=100(->112),C=256,H=8,dh=32
// R17: attn_fuse v8 -- parallel epilogue heads. Score computed from the oproj
//   f32 accumulator (lane dot + lr-shfl-reduce -> sc_part[8][112]); hbar from
//   the h1 accumulator (relu+row-sum in regs + lg-shfl-reduce); poly head
//   256-wide with group reduction. Removes the 3 serial scalar tails (~45k
//   VALU cyc/SIMD) and the h1->LDS pass. bias[2336] absorbs bs + bo_c.wsc
//   (wcomb). Main loop + kvproj v9 unchanged from R16.
// ---------------------------------------------------------------------------

typedef __attribute__((ext_vector_type(8))) short bf16x8;
typedef __attribute__((ext_vector_type(4))) float f32x4;

__device__ __forceinline__ float bf2f(ushort u) {
    union { float f; uint u32; } v; v.u32 = ((uint)u) << 16; return v.f;
}
__device__ __forceinline__ ushort f2bf(float f) {
    union { float f; uint u; } v; v.f = f;
    uint r = v.u + 0x7FFF + ((v.u >> 16) & 1);
    return (ushort)(r >> 16);
}
__device__ __forceinline__ uint pk2(float a, float b) {
    __hip_bfloat162 h = __float22bfloat162_rn(make_float2(a, b));
    union { __hip_bfloat162 h2; uint u; } c; c.h2 = h; return c.u;
}
__device__ __forceinline__ f32x4 MFMA(bf16x8 a, bf16x8 b, f32x4 c) {
    return __builtin_amdgcn_mfma_f32_16x16x32_bf16(a, b, c, 0, 0, 0);
}

#define SCALE_DH 0.17677669529663687f  // 1/sqrt(32)

// ---------------- prep: weights+biases -> ws tables, qcp zero ---------------
#define TOTALW (2337 * 256)
#define QCPN   (8 * 8 * 112 * 32)
#define NBIAS  2337

__global__ void prep_kernel(const float* w0, const float* w1_, const float* w2_,
                            const float* w3, const float* w4, const float* w5,
                            const float* w6, const float* w7, const float* w8,
                            const float* w9, const float* w10,
                            const float* b0, const float* b1_, const float* b2_,
                            const float* b3, const float* b4, const float* b5,
                            const float* b6, const float* b7, const float* b8,
                            const float* b9, const float* b10,
                            ushort* wbf, float* bias, ushort* qcp)
{
    for (size_t i = blockIdx.x * blockDim.x + threadIdx.x;
         i < (size_t)TOTALW + QCPN + NBIAS; i += (size_t)gridDim.x * blockDim.x) {
        if (i < TOTALW) {
            int row = (int)(i >> 8), col = (int)(i & 255);
            const float* sp; int base;
            if      (row < 256)  { sp = w0;  base = 0; }
            else if (row < 512)  { sp = w1_; base = 256; }
            else if (row < 768)  { sp = w2_; base = 512; }
            else if (row < 1024) { sp = w3;  base = 768; }
            else if (row < 1280) { sp = w4;  base = 1024; }
            else if (row < 1536) { sp = w5;  base = 1280; }
            else if (row < 1792) { sp = w6;  base = 1536; }
            else if (row < 2048) { sp = w7;  base = 1792; }
            else if (row < 2304) { sp = w8;  base = 2048; }
            else if (row < 2336) { sp = w9;  base = 2304; }
            else                 { sp = w10; base = 2336; }
            wbf[i] = f2bf(sp[(size_t)(row - base) * 256 + col]);
        } else if (i < (size_t)TOTALW + QCPN) {
            qcp[i - TOTALW] = 0;
        } else {
            int idx = (int)(i - TOTALW - QCPN);
            const float* sp; int base;
            if      (idx < 256)  { sp = b0;  base = 0; }
            else if (idx < 512)  { sp = b1_; base = 256; }
            else if (idx < 768)  { sp = b2_; base = 512; }
            else if (idx < 1024) { sp = b3;  base = 768; }
            else if (idx < 1280) { sp = b4;  base = 1024; }
            else if (idx < 1536) { sp = b5;  base = 1280; }
            else if (idx < 1792) { sp = b6;  base = 1536; }
            else if (idx < 2048) { sp = b7;  base = 1792; }
            else if (idx < 2304) { sp = b8;  base = 2048; }
            else if (idx < 2336) { sp = b9;  base = 2304; }
            else                 { sp = b10; base = 2336; }
            bias[idx] = sp[idx - base];
        }
    }
}

// ---------------- wcomb: M = wq_c @ wo_s -> wbf rows 1024..1279 -------------
// b' = bq_c + wq_c @ bo_s -> bias[1024..1279].
// bias[2336] = bs + bo_c . wsc (score-head constant fold).
__global__ __launch_bounds__(256)
void wcomb(const float* wq_c, const float* wo_s, const float* bq_c,
           const float* bo_s, const float* bo_c, const float* wsc,
           const float* bs, ushort* wbf, float* bias)
{
    __shared__ float row[256];
    int i = blockIdx.x, k = threadIdx.x;
    row[k] = wq_c[(size_t)i * 256 + k];
    __syncthreads();
    float acc = 0.f;
    for (int j = 0; j < 256; ++j)
        acc = fmaf(row[j], wo_s[(size_t)j * 256 + k], acc);
    wbf[(size_t)(1024 + i) * 256 + k] = f2bf(acc);
    if (k == 0) {
        float s = bq_c[i];
        for (int j = 0; j < 256; ++j) s += row[j] * bo_s[j];
        bias[1024 + i] = s;
    }
    if (i == 0 && k == 1) {
        float s = bs[0];
        for (int j = 0; j < 256; ++j) s += bo_c[j] * wsc[j];
        bias[2336] = s;
    }
}

// ---------------- generic small GEMM: out = A @ W^T + bias -----------------
template<int ASRC, int GS, int EPI>
__global__ __launch_bounds__(256)
void gemm_rows(const void* Aptr, const ushort* Wall, const float* Ball,
               ushort* Out, int M, int Wrow0, int Brow0, int ldo)
{
    __shared__ ushort As[64 * 40];
    __shared__ ushort Bs[128 * 40];
    int tid = threadIdx.x;
    int lane = tid & 63, w = tid >> 6;
    int lr = lane & 15, lg = lane >> 4;
    int r0 = blockIdx.x * 64;
    int j0 = blockIdx.y * 128;

    f32x4 acc[4][2];
    #pragma unroll
    for (int mt = 0; mt < 4; ++mt)
        #pragma unroll
        for (int nt = 0; nt < 2; ++nt) { f32x4 z = {0.f,0.f,0.f,0.f}; acc[mt][nt] = z; }

    for (int ks = 0; ks < 8; ++ks) {
        int c0 = ks * 32;
        {
            int i = tid >> 2, q = tid & 3;
            int r = r0 + i;
            if (ASRC == 0) {
                uint4 v = make_uint4(0u,0u,0u,0u);
                if (r < M) v = *(const uint4*)((const ushort*)Aptr + (size_t)r * 256 + c0 + q * 8);
                *(uint4*)(&As[i * 40 + q * 8]) = v;
            } else {
                uint u[4] = {0u,0u,0u,0u};
                if (r < M) {
                    int g = r / GS, o = r - g * GS;
                    const float* src = (const float*)Aptr + (size_t)g * 256 * GS + o;
                    #pragma unroll
                    for (int k2 = 0; k2 < 4; ++k2) {
                        ushort a0 = f2bf(src[(size_t)(c0 + q * 8 + 2 * k2)     * GS]);
                        ushort a1 = f2bf(src[(size_t)(c0 + q * 8 + 2 * k2 + 1) * GS]);
                        u[k2] = (uint)a0 | ((uint)a1 << 16);
                    }
                }
                *(uint4*)(&As[i * 40 + q * 8]) = make_uint4(u[0], u[1], u[2], u[3]);
            }
        }
        {
            int jj = tid >> 1, half = tid & 1;
            const ushort* src = Wall + (size_t)(Wrow0 + j0 + jj) * 256 + c0 + half * 16;
            ushort* dst = &Bs[jj * 40 + half * 16];
            *(uint4*)(dst)     = *(const uint4*)(src);
            *(uint4*)(dst + 8) = *(const uint4*)(src + 8);
        }
        __syncthreads();
        bf16x8 bfr[2];
        #pragma unroll
        for (int nt = 0; nt < 2; ++nt)
            bfr[nt] = *(const bf16x8*)(&Bs[(w * 32 + nt * 16 + lr) * 40 + lg * 8]);
        #pragma unroll
        for (int mt = 0; mt < 4; ++mt) {
            bf16x8 afr = *(const bf16x8*)(&As[(mt * 16 + lr) * 40 + lg * 8]);
            acc[mt][0] = MFMA(afr, bfr[0], acc[mt][0]);
            acc[mt][1] = MFMA(afr, bfr[1], acc[mt][1]);
        }
        __syncthreads();
    }
    #pragma unroll
    for (int mt = 0; mt < 4; ++mt) {
        #pragma unroll
        for (int nt = 0; nt < 2; ++nt) {
            int jc = j0 + w * 32 + nt * 16 + lr;
            float bias = Ball[Brow0 + jc];
            #pragma unroll
            for (int rg = 0; rg < 4; ++rg) {
                int r = r0 + mt * 16 + lg * 4 + rg;
                if (r >= M) continue;
                float vv = acc[mt][nt][rg] + bias;
                if (EPI == 0) {
                    Out[(size_t)r * ldo + jc] = f2bf(vv);
                } else {
                    int b = r / 100, s = r - b * 100;
                    int h = jc >> 5, d = jc & 31;
                    Out[(((size_t)(b * 8 + h)) * 112 + s) * 32 + d] = f2bf(vv * SCALE_DH);
                }
            }
        }
    }
}

// ---------------- self-attention (tiny, VALU) ------------------------------
__global__ __launch_bounds__(128)
void self_attn(const ushort* qkv, ushort* sav)
{
    __shared__ float kls[100][33];
    __shared__ float vls[100][33];
    __shared__ float sls[100][101];
    int bh = blockIdx.x; int b = bh >> 3, h = bh & 7;
    int tid = threadIdx.x;
    for (int idx = tid; idx < 100 * 32; idx += 128) {
        int t = idx >> 5, d = idx & 31;
        kls[t][d] = bf2f(qkv[((size_t)(b * 100 + t)) * 768 + 256 + h * 32 + d]);
        vls[t][d] = bf2f(qkv[((size_t)(b * 100 + t)) * 768 + 512 + h * 32 + d]);
    }
    __syncthreads();
    if (tid < 100) {
        int s = tid;
        float q[32];
        #pragma unroll
        for (int d = 0; d < 32; ++d)
            q[d] = bf2f(qkv[((size_t)(b * 100 + s)) * 768 + h * 32 + d]) * SCALE_DH;
        float mx = -1e30f;
        for (int t = 0; t < 100; ++t) {
            float sc = 0.f;
            #pragma unroll
            for (int d = 0; d < 32; ++d) sc += q[d] * kls[t][d];
            sls[s][t] = sc; mx = fmaxf(mx, sc);
        }
        float sum = 0.f;
        for (int t = 0; t < 100; ++t) {
            float p = __expf(sls[s][t] - mx);
            sls[s][t] = p; sum += p;
        }
        float inv = 1.f / sum;
        float acc2[32];
        #pragma unroll
        for (int d = 0; d < 32; ++d) acc2[d] = 0.f;
        for (int t = 0; t < 100; ++t) {
            float pv = sls[s][t];
            #pragma unroll
            for (int d = 0; d < 32; ++d) acc2[d] += pv * vls[t][d];
        }
        #pragma unroll
        for (int d = 0; d < 32; ++d)
            sav[((size_t)(b * 100 + s)) * 256 + h * 32 + d] = f2bf(acc2[d] * inv);
    }
}

// ---------------- kvproj v9: kc[n][224][256] t-major, vc[n][256][224] ------
__global__ __launch_bounds__(512, 2)
void kvproj(const float* features, const ushort* Wall, const float* Ball,
            ushort* kc, ushort* vc, int n_base)
{
    __shared__ ushort featT[224 * 264];
    int tid = threadIdx.x;
    int lane = tid & 63, w = tid >> 6;
    int lr = lane & 15, lg = lane >> 4;
    int nl = blockIdx.x;
    int n  = n_base + nl;
    const float* fb = features + (size_t)n * 256 * 196;

    bf16x8 af[4][8];
    #pragma unroll
    for (int m = 0; m < 4; ++m) {
        int row = ((m < 2) ? 1280 : 1536) + w * 32 + (m & 1) * 16 + lr;
        #pragma unroll
        for (int ks = 0; ks < 8; ++ks)
            af[m][ks] = *(const bf16x8*)(Wall + (size_t)row * 256 + ks * 32 + lg * 8);
    }
    float biask0 = Ball[1280 + w * 32 + lr];
    float biask1 = Ball[1296 + w * 32 + lr];
    float biasv0 = Ball[1536 + w * 32 + lr];
    float biasv1 = Ball[1552 + w * 32 + lr];

    #pragma unroll
    for (int it = 0; it < 7; ++it) {
        int idx = tid + it * 512;
        if (idx < 3136) {
            int cg = idx / 49, tq = idx - cg * 49;
            const float* p = fb + (size_t)(cg * 4) * 196 + tq * 4;
            float4 v0 = *(const float4*)(p);
            float4 v1 = *(const float4*)(p + 196);
            float4 v2 = *(const float4*)(p + 392);
            float4 v3 = *(const float4*)(p + 588);
            #pragma unroll
            for (int j = 0; j < 4; ++j) {
                float e0 = (j == 0) ? v0.x : (j == 1) ? v0.y : (j == 2) ? v0.z : v0.w;
                float e1 = (j == 0) ? v1.x : (j == 1) ? v1.y : (j == 2) ? v1.z : v1.w;
                float e2 = (j == 0) ? v2.x : (j == 1) ? v2.y : (j == 2) ? v2.z : v2.w;
                float e3 = (j == 0) ? v3.x : (j == 1) ? v3.y : (j == 2) ? v3.z : v3.w;
                uint2 pr;
                pr.x = pk2(e0, e1);
                pr.y = pk2(e2, e3);
                *(uint2*)(&featT[(tq * 4 + j) * 264 + cg * 4]) = pr;
            }
        }
    }
    for (int idx = tid; idx < 12 * 264; idx += 512)
        featT[196 * 264 + idx] = 0;
    __syncthreads();   // the only barrier

    for (int tt = 0; tt < 13; ++tt) {
        bf16x8 a8[8];
        #pragma unroll
        for (int ks = 0; ks < 8; ++ks)
            a8[ks] = *(const bf16x8*)(&featT[(tt * 16 + lr) * 264 + ks * 32 + lg * 8]);
        f32x4 acc[4];
        #pragma unroll
        for (int m = 0; m < 4; ++m) { f32x4 z = {0.f,0.f,0.f,0.f}; acc[m] = z; }
        #pragma unroll
        for (int ks = 0; ks < 8; ++ks)
            #pragma unroll
            for (int m = 0; m < 4; ++m)
                acc[m] = MFMA(a8[ks], af[m][ks], acc[m]);

        int tb = tt * 16 + lg * 4;
        #pragma unroll
        for (int rg = 0; rg < 4; ++rg) {
            int t = tb + rg;
            if (t < 196) {
                kc[((size_t)nl * 224 + t) * 256 + w * 32 + lr]      = f2bf(acc[0][rg] + biask0);
                kc[((size_t)nl * 224 + t) * 256 + w * 32 + 16 + lr] = f2bf(acc[1][rg] + biask1);
            }
        }
        if (tb < 196) {
            size_t vb0 = ((size_t)nl * 256 + w * 32 + lr) * 224 + tb;
            size_t vb1 = ((size_t)nl * 256 + w * 32 + 16 + lr) * 224 + tb;
            uint a01 = pk2(acc[2][0] + biasv0, acc[2][1] + biasv0);
            uint a23 = pk2(acc[2][2] + biasv0, acc[2][3] + biasv0);
            uint b01 = pk2(acc[3][0] + biasv1, acc[3][1] + biasv1);
            uint b23 = pk2(acc[3][2] + biasv1, acc[3][3] + biasv1);
            *(uint*)(vc + vb0)     = a01;
            *(uint*)(vc + vb0 + 2) = a23;
            *(uint*)(vc + vb1)     = b01;
            *(uint*)(vc + vb1 + 2) = b23;
        }
    }
}

// ---------------- attn_fuse v8: parallel epilogue heads --------------------
// block 512 (8 waves, wave = head), (512,2). Main loop = R16 v7 (zero-LDS,
// swapped QK^T, depth-2 prefetch, setprio). Epilogue: score from oproj f32
// accumulator (lr-shfl reduce -> sc_part), hbar from h1 accumulator
// (lg-shfl reduce), poly 256-wide. LDS: OL @0 | hbar @59392 | scb @60416 |
// sc_part @60864 | pp @64448 | O2 @71680.
__global__ __launch_bounds__(512, 2)
void attn_fuse(const ushort* qcp, const ushort* kc, const ushort* vc,
               const ushort* Wall, const float* Ball, float* outp, int n_base)
{
    __shared__ char smem[130816];
    ushort* OL     = (ushort*)smem;
    float* hbar    = (float*)(smem + 59392);
    float* scb     = (float*)(smem + 60416);
    float* sc_part = (float*)(smem + 60864);
    float* pp      = (float*)(smem + 64448);
    ushort* O2     = (ushort*)(smem + 71680);

    int tid = threadIdx.x;
    int lane = tid & 63; int w = tid >> 6;             // w = head
    int lr = lane & 15, lg = lane >> 4;
    int nl = blockIdx.x; int n = n_base + nl;
    int b = n >> 6;
    const ushort* kcn = kc + (size_t)nl * 224 * 256;
    const ushort* vcn = vc + (size_t)nl * 256 * 224;

    bf16x8 qf[7];
    #pragma unroll
    for (int mt = 0; mt < 7; ++mt)
        qf[mt] = *(const bf16x8*)(qcp + ((((size_t)(b * 8 + w)) * 112 + mt * 16 + lr) * 32 + lg * 8));

    bf16x8 ones;
    #pragma unroll
    for (int j = 0; j < 8; ++j) ones[j] = (short)0x3F80;

    f32x4 o_acc[7][2], l_acc[7];
    #pragma unroll
    for (int mt = 0; mt < 7; ++mt) {
        f32x4 z = {0.f,0.f,0.f,0.f};
        o_acc[mt][0] = z; o_acc[mt][1] = z; l_acc[mt] = z;
    }

    const ushort* kbase = kcn + (size_t)lr * 256 + w * 32 + lg * 8;
    const ushort* vrow0 = vcn + ((size_t)(w * 32 + lr)) * 224;
    const ushort* vrow1 = vcn + ((size_t)(w * 32 + 16 + lr)) * 224;

    bf16x8 k0[3], k1[3];
    uint2 va[3], vb[3], vcq[3], vd[3];
    #pragma unroll
    for (int pc = 0; pc < 2; ++pc) {
        int t0n = pc * 32;
        k0[pc] = *(const bf16x8*)(kbase + (size_t)t0n * 256);
        k1[pc] = *(const bf16x8*)(kbase + (size_t)(t0n + 16) * 256);
        va[pc]  = *(const uint2*)(vrow0 + t0n + 4 * lg);
        vb[pc]  = *(const uint2*)(vrow0 + t0n + 16 + 4 * lg);
        vcq[pc] = *(const uint2*)(vrow1 + t0n + 4 * lg);
        vd[pc]  = *(const uint2*)(vrow1 + t0n + 16 + 4 * lg);
    }

    #pragma unroll
    for (int ch = 0; ch < 7; ++ch) {
        const int cur = ch % 3;
        int t0 = ch * 32;
        if (ch + 2 < 7) {
            const int nx = (ch + 2) % 3;
            int t0n = (ch + 2) * 32;
            k0[nx] = *(const bf16x8*)(kbase + (size_t)t0n * 256);
            k1[nx] = *(const bf16x8*)(kbase + (size_t)(t0n + 16) * 256);
            va[nx]  = *(const uint2*)(vrow0 + t0n + 4 * lg);
            vb[nx]  = *(const uint2*)(vrow0 + t0n + 16 + 4 * lg);
            vcq[nx] = *(const uint2*)(vrow1 + t0n + 4 * lg);
            vd[nx]  = *(const uint2*)(vrow1 + t0n + 16 + 4 * lg);
            if (t0n == 192) {
                uint2 zz = make_uint2(0u, 0u);
                vb[nx] = zz; vd[nx] = zz;
                if (lg) { va[nx] = zz; vcq[nx] = zz; }
            }
        }
        union { uint4 q; bf16x8 v; } u0, u1;
        u0.q = make_uint4(va[cur].x, va[cur].y, vb[cur].x, vb[cur].y);
        u1.q = make_uint4(vcq[cur].x, vcq[cur].y, vd[cur].x, vd[cur].y);
        bool mA[4], mB[4];
        #pragma unroll
        for (int r = 0; r < 4; ++r) {
            mA[r] = (t0 + 4 * lg + r)      >= 196;
            mB[r] = (t0 + 16 + 4 * lg + r) >= 196;
        }
        __builtin_amdgcn_s_setprio(1);
        #pragma unroll
        for (int mt = 0; mt < 7; ++mt) {
            f32x4 z = {0.f,0.f,0.f,0.f};
            f32x4 s0 = MFMA(k0[cur], qf[mt], z);
            f32x4 s1 = MFMA(k1[cur], qf[mt], z);
            float p00 = mA[0] ? 0.f : __expf(s0[0]);
            float p01 = mA[1] ? 0.f : __expf(s0[1]);
            float p02 = mA[2] ? 0.f : __expf(s0[2]);
            float p03 = mA[3] ? 0.f : __expf(s0[3]);
            float p10 = mB[0] ? 0.f : __expf(s1[0]);
            float p11 = mB[1] ? 0.f : __expf(s1[1]);
            float p12 = mB[2] ? 0.f : __expf(s1[2]);
            float p13 = mB[3] ? 0.f : __expf(s1[3]);
            union { uint4 q; bf16x8 v; } pu;
            pu.q.x = pk2(p00, p01);
            pu.q.y = pk2(p02, p03);
            pu.q.z = pk2(p10, p11);
            pu.q.w = pk2(p12, p13);
            o_acc[mt][0] = MFMA(pu.v, u0.v, o_acc[mt][0]);
            o_acc[mt][1] = MFMA(pu.v, u1.v, o_acc[mt][1]);
            l_acc[mt]    = MFMA(pu.v, ones, l_acc[mt]);
        }
        __builtin_amdgcn_s_setprio(0);
    }

    // normalized O -> OL[112][264] (wave-private columns)
    #pragma unroll
    for (int mt = 0; mt < 7; ++mt) {
        #pragma unroll
        for (int r = 0; r < 4; ++r) {
            float inv = 1.f / l_acc[mt][r];
            int srow = mt * 16 + lg * 4 + r;
            OL[srow * 264 + w * 32 + lr]      = f2bf(o_acc[mt][0][r] * inv);
            OL[srow * 264 + w * 32 + 16 + lr] = f2bf(o_acc[mt][1][r] * inv);
        }
    }
    __syncthreads();

    // oproj: a2 = OL @ wo_c^T; score partials from a2 (f32 O2)
    {
        f32x4 a2[7][2];
        #pragma unroll
        for (int mt = 0; mt < 7; ++mt) {
            f32x4 z = {0.f,0.f,0.f,0.f}; a2[mt][0] = z; a2[mt][1] = z;
        }
        for (int ks = 0; ks < 8; ++ks) {
            int c0 = ks * 32;
            bf16x8 bw0 = *(const bf16x8*)(Wall + (size_t)(1792 + w * 32 + lr) * 256 + c0 + lg * 8);
            bf16x8 bw1 = *(const bf16x8*)(Wall + (size_t)(1792 + w * 32 + 16 + lr) * 256 + c0 + lg * 8);
            #pragma unroll
            for (int mt = 0; mt < 7; ++mt) {
                bf16x8 afr = *(const bf16x8*)(&OL[(mt * 16 + lr) * 264 + c0 + lg * 8]);
                a2[mt][0] = MFMA(afr, bw0, a2[mt][0]);
                a2[mt][1] = MFMA(afr, bw1, a2[mt][1]);
            }
        }
        // score partials: lane dot over its 2 cols, reduce across lr group
        float wscA = bf2f(Wall[(size_t)2336 * 256 + w * 32 + lr]);
        float wscB = bf2f(Wall[(size_t)2336 * 256 + w * 32 + 16 + lr]);
        #pragma unroll
        for (int mt = 0; mt < 7; ++mt) {
            float sv0 = a2[mt][0][0] * wscA + a2[mt][1][0] * wscB;
            float sv1 = a2[mt][0][1] * wscA + a2[mt][1][1] * wscB;
            float sv2 = a2[mt][0][2] * wscA + a2[mt][1][2] * wscB;
            float sv3 = a2[mt][0][3] * wscA + a2[mt][1][3] * wscB;
            sv0 += __shfl_xor(sv0, 1); sv0 += __shfl_xor(sv0, 2);
            sv0 += __shfl_xor(sv0, 4); sv0 += __shfl_xor(sv0, 8);
            sv1 += __shfl_xor(sv1, 1); sv1 += __shfl_xor(sv1, 2);
            sv1 += __shfl_xor(sv1, 4); sv1 += __shfl_xor(sv1, 8);
            sv2 += __shfl_xor(sv2, 1); sv2 += __shfl_xor(sv2, 2);
            sv2 += __shfl_xor(sv2, 4); sv2 += __shfl_xor(sv2, 8);
            sv3 += __shfl_xor(sv3, 1); sv3 += __shfl_xor(sv3, 2);
            sv3 += __shfl_xor(sv3, 4); sv3 += __shfl_xor(sv3, 8);
            if (lr == 0) {
                int sb = w * 112 + mt * 16 + lg * 4;
                sc_part[sb]     = sv0;
                sc_part[sb + 1] = sv1;
                sc_part[sb + 2] = sv2;
                sc_part[sb + 3] = sv3;
            }
        }
        // O2 write (bf16) for the h1 GEMM
        float biasA = Ball[1792 + w * 32 + lr];
        float biasB = Ball[1792 + w * 32 + 16 + lr];
        #pragma unroll
        for (int mt = 0; mt < 7; ++mt)
            #pragma unroll
            for (int r = 0; r < 4; ++r) {
                int srow = mt * 16 + lg * 4 + r;
                O2[srow * 264 + w * 32 + lr]      = f2bf(a2[mt][0][r] + biasA);
                O2[srow * 264 + w * 32 + 16 + lr] = f2bf(a2[mt][1][r] + biasB);
            }
    }
    __syncthreads();   // O2 + sc_part ready

    // h1 accumulate (reads O2); hbar from registers; score finalize
    {
        f32x4 a2[7][2];
        #pragma unroll
        for (int mt = 0; mt < 7; ++mt) {
            f32x4 z = {0.f,0.f,0.f,0.f}; a2[mt][0] = z; a2[mt][1] = z;
        }
        for (int ks = 0; ks < 8; ++ks) {
            int c0 = ks * 32;
            bf16x8 bw0 = *(const bf16x8*)(Wall + (size_t)(2048 + w * 32 + lr) * 256 + c0 + lg * 8);
            bf16x8 bw1 = *(const bf16x8*)(Wall + (size_t)(2048 + w * 32 + 16 + lr) * 256 + c0 + lg * 8);
            #pragma unroll
            for (int mt = 0; mt < 7; ++mt) {
                bf16x8 afr = *(const bf16x8*)(&O2[(mt * 16 + lr) * 264 + c0 + lg * 8]);
                a2[mt][0] = MFMA(afr, bw0, a2[mt][0]);
                a2[mt][1] = MFMA(afr, bw1, a2[mt][1]);
            }
        }
        float biasA = Ball[2048 + w * 32 + lr];
        float biasB = Ball[2048 + w * 32 + 16 + lr];
        float hA = 0.f, hB = 0.f;
        #pragma unroll
        for (int mt = 0; mt < 7; ++mt)
            #pragma unroll
            for (int r = 0; r < 4; ++r) {
                int srow = mt * 16 + lg * 4 + r;
                if (srow < 100) {
                    float vA = a2[mt][0][r] + biasA; vA = vA > 0.f ? vA : 0.f;
                    float vB = a2[mt][1][r] + biasB; vB = vB > 0.f ? vB : 0.f;
                    hA += vA; hB += vB;
                }
            }
        hA += __shfl_xor(hA, 16); hA += __shfl_xor(hA, 32);
        hB += __shfl_xor(hB, 16); hB += __shfl_xor(hB, 32);
        if (lg == 0) {
            hbar[w * 32 + lr]      = hA * 0.01f;
            hbar[w * 32 + 16 + lr] = hB * 0.01f;
        }
        if (tid < 100) {
            float s = 0.f;
            #pragma unroll
            for (int ww = 0; ww < 8; ++ww) s += sc_part[ww * 112 + tid];
            s += Ball[2336];
            scb[tid] = 1.f / (1.f + __expf(-s));
        }
    }
    __syncthreads();   // hbar + scb ready

    // poly partials (256-wide) + score mean
    if (tid < 256) {
        int g = tid >> 5, k = tid & 31;
        float s = 0.f;
        #pragma unroll
        for (int c2 = 0; c2 < 32; ++c2)
            s += hbar[g * 32 + c2] * bf2f(Wall[(size_t)(2304 + k) * 256 + g * 32 + c2]);
        pp[tid] = s;
    }
    if (tid == 320) {
        float s = 0.f;
        for (int i2 = 0; i2 < 100; ++i2) s += scb[i2];
        outp[16384 + n] = s * 0.01f;
    }
    __syncthreads();
    if (tid < 32) {
        float s = Ball[2304 + tid];
        #pragma unroll
        for (int g = 0; g < 8; ++g) s += pp[g * 32 + tid];
        outp[(size_t)n * 32 + tid] = s;
    }
}

// ---------------------------------------------------------------------------
extern "C" void kernel_launch(void* const* d_in, const int* in_sizes, int n_in,
                              void* d_out, int out_size, void* d_ws, size_t ws_size,
                              hipStream_t stream)
{
    const float* features = (const float*)d_in[0];
    const float* qfeat    = (const float*)d_in[1];
    char* ws = (char*)d_ws;

    ushort* wbf  = (ushort*)ws;                    //  2337*256 bf16
    float*  bias = (float*)(ws + 1196544);         //  2337 f32
    ushort* qkv  = (ushort*)(ws + 1206016);        //  800*768
    ushort* sav  = (ushort*)(ws + 2434816);        //  800*256
    ushort* qcp  = (ushort*)(ws + 3254016);        //  8*8*112*32
    ushort* kvb  = (ushort*)(ws + 3712768);

    prep_kernel<<<dim3(512), dim3(256), 0, stream>>>(
        (const float*)d_in[2], (const float*)d_in[3], (const float*)d_in[4],
        (const float*)d_in[8], (const float*)d_in[10], (const float*)d_in[11],
        (const float*)d_in[12], (const float*)d_in[16], (const float*)d_in[18],
        (const float*)d_in[20], (const float*)d_in[22],
        (const float*)d_in[5], (const float*)d_in[6], (const float*)d_in[7],
        (const float*)d_in[9], (const float*)d_in[13], (const float*)d_in[14],
        (const float*)d_in[15], (const float*)d_in[17], (const float*)d_in[19],
        (const float*)d_in[21], (const float*)d_in[23],
        wbf, bias, qcp);

    // fold wq_c @ wo_s into M; score-head constant into bias[2336]
    wcomb<<<dim3(256), dim3(256), 0, stream>>>(
        (const float*)d_in[10], (const float*)d_in[8],
        (const float*)d_in[13], (const float*)d_in[9],
        (const float*)d_in[17], (const float*)d_in[22],
        (const float*)d_in[23], wbf, bias);

    // self-attention chain (G2+G3 folded into one GEMM via M)
    gemm_rows<1, 100, 0><<<dim3(13, 6), dim3(256), 0, stream>>>(
        qfeat, wbf, bias, qkv, 800, 0, 0, 768);
    self_attn<<<dim3(64), dim3(128), 0, stream>>>(qkv, sav);
    gemm_rows<0, 1, 1><<<dim3(13, 2), dim3(256), 0, stream>>>(
        sav, wbf, bias, qcp, 800, 1024, 1024, 0);

    // cross-attention, pass-split on workspace budget
    const size_t per_n = 229376;               // bytes of kc+vc per proposal
    long avail = (long)ws_size - 3712768L;
    int Np = 512;
    if (avail < (long)(per_n * 512)) {
        Np = (int)(avail / (long)per_n);
        if (Np < 1) Np = 1;
    }
    ushort* kcb = kvb;                                   // [Np][224][256]
    ushort* vcb = kvb + (size_t)Np * 224 * 256;          // [Np][256][224]
    float* outp = (float*)d_out;
    for (int n0 = 0; n0 < 512; n0 += Np) {
        int cnt = (512 - n0 < Np) ? (512 - n0) : Np;
        kvproj<<<dim3(cnt), dim3(512), 0, stream>>>(features, wbf, bias, kcb, vcb, n0);
        attn_fuse<<<dim3(cnt), dim3(512), 0, stream>>>(qcp, kcb, vcb, wbf, bias, outp, n0);
    }
}